// Round 2
// baseline (4882.722 us; speedup 1.0000x reference)
//
#include <hip/hip_runtime.h>
#include <hip/hip_bf16.h>
#include <stdint.h>

#define N_NODES 50000
#define N_EDGES 1000000
#define HIDDEN 128

using short8  = __attribute__((ext_vector_type(8))) short;
using floatx4 = __attribute__((ext_vector_type(4))) float;

__device__ __forceinline__ float bf2f(uint16_t u) {
    return __uint_as_float(((uint32_t)u) << 16);
}
__device__ __forceinline__ uint16_t f2bf(float f) {
    uint32_t x = __float_as_uint(f);
    return (uint16_t)((x + 0x7FFFu + ((x >> 16) & 1u)) >> 16);
}
__device__ __forceinline__ uint32_t cvt_pk_bf16(float lo, float hi) {
    uint32_t r;
    asm("v_cvt_pk_bf16_f32 %0, %1, %2" : "=v"(r) : "v"(lo), "v"(hi));
    return r;
}
__device__ __forceinline__ float fast_silu(float x) {
    float e = __expf(-x);
    return x * __builtin_amdgcn_rcpf(1.0f + e);
}

// ---------------------------------------------------------------------------
// Kernel 1: At[n][k] = sum_j h[n][j]*W1[j][k] + b1[k]   (k<128)
//           Bt[n][k] = sum_j h[n][j]*W1[128+j][k]
// ---------------------------------------------------------------------------
__global__ __launch_bounds__(256) void precompute_AB(
    const float* __restrict__ h, const float* __restrict__ W1,
    const float* __restrict__ b1,
    uint16_t* __restrict__ At, uint16_t* __restrict__ Bt)
{
    __shared__ uint16_t w1t[256 * 128];  // [c][j] bf16, XOR-swizzled, 64 KB
    int t = threadIdx.x;
    for (int idx = t; idx < 256 * 128; idx += 256) {
        int c = idx >> 7, j = idx & 127;
        float v = (c < 128) ? W1[j * 128 + c] : W1[(128 + j) * 128 + (c - 128)];
        int byte_off = (c << 8) + (j << 1);
        byte_off ^= ((c & 7) << 4);
        *(uint16_t*)((char*)w1t + byte_off) = f2bf(v);
    }
    __syncthreads();

    int wave = t >> 6, lane = t & 63;
    int lrow = lane & 15, kg = lane >> 4;

    int nodeBase = blockIdx.x * 64 + wave * 16;
    int node = nodeBase + lrow;
    int nclamp = node < N_NODES ? node : N_NODES - 1;
    const float* hrow = h + (size_t)nclamp * 128;

    short8 afrag[4];
#pragma unroll
    for (int kk = 0; kk < 4; ++kk) {
        int k0 = kk * 32 + kg * 8;
        float4 f0 = *(const float4*)(hrow + k0);
        float4 f1 = *(const float4*)(hrow + k0 + 4);
        short8 a;
        uint32_t* ap = (uint32_t*)&a;
        ap[0] = cvt_pk_bf16(f0.x, f0.y);
        ap[1] = cvt_pk_bf16(f0.z, f0.w);
        ap[2] = cvt_pk_bf16(f1.x, f1.y);
        ap[3] = cvt_pk_bf16(f1.z, f1.w);
        afrag[kk] = a;
    }

    for (int nt = 0; nt < 16; ++nt) {
        floatx4 acc = {0.f, 0.f, 0.f, 0.f};
        int c = nt * 16 + lrow;
#pragma unroll
        for (int kk = 0; kk < 4; ++kk) {
            int byte_off = (c << 8) + ((kk * 32 + kg * 8) << 1);
            byte_off ^= ((c & 7) << 4);
            short8 b = *(const short8*)((const char*)w1t + byte_off);
            acc = __builtin_amdgcn_mfma_f32_16x16x32_bf16(afrag[kk], b, acc, 0, 0, 0);
        }
#pragma unroll
        for (int r = 0; r < 4; ++r) {
            int onode = nodeBase + kg * 4 + r;
            if (onode < N_NODES) {
                float v = acc[r];
                if (c < 128) {
                    At[(size_t)onode * 128 + c] = f2bf(v + b1[c]);
                } else {
                    Bt[(size_t)onode * 128 + (c - 128)] = f2bf(v);
                }
            }
        }
    }
}

// ---------------------------------------------------------------------------
// Kernel 2: per-edge fused MLP. One wave = 16 edges; software-pipelined
// gathers (next tile's At/Bt rows issued before current tile's layer-2).
// ---------------------------------------------------------------------------
__global__ __launch_bounds__(256, 3) void edge_kernel(
    const int* __restrict__ rowIdx, const int* __restrict__ colIdx,
    const float* __restrict__ edge_attr, const float* __restrict__ edge_mask,
    const float* __restrict__ coord_diff,
    const float* __restrict__ W1, const float* __restrict__ W2,
    const float* __restrict__ b2, const float* __restrict__ W3,
    const uint16_t* __restrict__ At, const uint16_t* __restrict__ Bt,
    float* __restrict__ agg)
{
    __shared__ uint16_t w2t[128 * 128];  // [n][k] bf16, XOR-swizzled, 32 KB
    __shared__ float s_w1e[128], s_b2[128], s_w3[128];
    int t = threadIdx.x;
    for (int idx = t; idx < 128 * 128; idx += 256) {
        int n = idx >> 7, k = idx & 127;
        float v = W2[k * 128 + n];
        int byte_off = (n << 8) + (k << 1);
        byte_off ^= ((n & 7) << 4);
        *(uint16_t*)((char*)w2t + byte_off) = f2bf(v);
    }
    if (t < 128) { s_w1e[t] = W1[256 * 128 + t]; s_b2[t] = b2[t]; s_w3[t] = W3[t]; }
    __syncthreads();

    int wave = t >> 6, lane = t & 63;
    int lrow = lane & 15, kg = lane >> 4;

    const int numTiles = N_EDGES / 16;           // 62500
    int wavesTotal = gridDim.x * 4;
    int waveId = blockIdx.x * 4 + wave;
    if (waveId >= numTiles) return;

    // ---- prologue: load tile-0 indices + gathers ----
    int tile = waveId;
    int e0 = tile * 16 + lrow;
    int r = rowIdx[e0], c = colIdx[e0];
    float attr = edge_attr[e0];
    short8 ga[4], gb[4];
    {
        const uint16_t* arow = At + (size_t)r * 128;
        const uint16_t* brow = Bt + (size_t)c * 128;
#pragma unroll
        for (int kk = 0; kk < 4; ++kk) {
            int k0 = kk * 32 + kg * 8;
            ga[kk] = *(const short8*)(arow + k0);
            gb[kk] = *(const short8*)(brow + k0);
        }
    }

    while (true) {
        int ebase = tile * 16;
        int ntile = tile + wavesTotal;
        bool more = ntile < numTiles;
        int tclamp = more ? ntile : tile;
        // next tile's indices (latency hidden under layer-1)
        int ne = tclamp * 16 + lrow;
        int nr = rowIdx[ne], nc = colIdx[ne];
        float nattr = edge_attr[ne];

        // ---- layer 1: consume ga/gb -> afrag (silu'd bf16) ----
        short8 afrag[4];
#pragma unroll
        for (int kk = 0; kk < 4; ++kk) {
            int k0 = kk * 32 + kg * 8;
            float xs[8];
#pragma unroll
            for (int j = 0; j < 8; ++j) {
                float x = bf2f((uint16_t)ga[kk][j]) + bf2f((uint16_t)gb[kk][j])
                        + attr * s_w1e[k0 + j];
                xs[j] = fast_silu(x);
            }
            short8 u;
            uint32_t* up = (uint32_t*)&u;
            up[0] = cvt_pk_bf16(xs[0], xs[1]);
            up[1] = cvt_pk_bf16(xs[2], xs[3]);
            up[2] = cvt_pk_bf16(xs[4], xs[5]);
            up[3] = cvt_pk_bf16(xs[6], xs[7]);
            afrag[kk] = u;
        }

        // ---- issue next tile's gathers (hidden under layer-2) ----
        {
            const uint16_t* narow = At + (size_t)nr * 128;
            const uint16_t* nbrow = Bt + (size_t)nc * 128;
#pragma unroll
            for (int kk = 0; kk < 4; ++kk) {
                int k0 = kk * 32 + kg * 8;
                ga[kk] = *(const short8*)(narow + k0);
                gb[kk] = *(const short8*)(nbrow + k0);
            }
        }

        // ---- layer 2 + fused silu + W3 dot ----
        float pm0 = 0.f, pm1 = 0.f, pm2 = 0.f, pm3 = 0.f;
#pragma unroll
        for (int nt = 0; nt < 8; ++nt) {
            floatx4 acc = {0.f, 0.f, 0.f, 0.f};
            int n = nt * 16 + lrow;
#pragma unroll
            for (int kk = 0; kk < 4; ++kk) {
                int byte_off = (n << 8) + ((kk * 32 + kg * 8) << 1);
                byte_off ^= ((n & 7) << 4);
                short8 b = *(const short8*)((const char*)w2t + byte_off);
                acc = __builtin_amdgcn_mfma_f32_16x16x32_bf16(afrag[kk], b, acc, 0, 0, 0);
            }
            float w3v = s_w3[n], b2v = s_b2[n];
            pm0 += fast_silu(acc[0] + b2v) * w3v;
            pm1 += fast_silu(acc[1] + b2v) * w3v;
            pm2 += fast_silu(acc[2] + b2v) * w3v;
            pm3 += fast_silu(acc[3] + b2v) * w3v;
        }

        // reduce across the 16 lanes of each group
#pragma unroll
        for (int m = 1; m < 16; m <<= 1) {
            pm0 += __shfl_xor(pm0, m, 64);
            pm1 += __shfl_xor(pm1, m, 64);
            pm2 += __shfl_xor(pm2, m, 64);
            pm3 += __shfl_xor(pm3, m, 64);
        }
        // group kg holds m for edges ebase + kg*4 + {0..3} in pm0..pm3

        if (lrow < 12) {
            int rsel = lrow / 3;
            int dim = lrow - rsel * 3;
            float mval = (rsel == 0) ? pm0 : (rsel == 1) ? pm1 : (rsel == 2) ? pm2 : pm3;
            int eg = ebase + kg * 4 + rsel;
            float val = coord_diff[eg * 3 + dim] * mval * edge_mask[eg];
            int rnode = __shfl(r, kg * 4 + rsel, 16);
            atomicAdd(&agg[rnode * 3 + dim], val);
        }

        if (!more) break;
        tile = ntile;
        r = nr; c = nc; attr = nattr;
    }
}

// ---------------------------------------------------------------------------
// Kernel 3: out = (coord + agg/100) * node_mask
// ---------------------------------------------------------------------------
__global__ __launch_bounds__(256) void finalize_kernel(
    const float* __restrict__ coord, const float* __restrict__ agg,
    const float* __restrict__ node_mask, float* __restrict__ out)
{
    int i = blockIdx.x * 256 + threadIdx.x;
    if (i < N_NODES * 3) {
        out[i] = (coord[i] + agg[i] * 0.01f) * node_mask[i / 3];
    }
}

extern "C" void kernel_launch(void* const* d_in, const int* in_sizes, int n_in,
                              void* d_out, int out_size, void* d_ws, size_t ws_size,
                              hipStream_t stream) {
    const float* h          = (const float*)d_in[0];
    const float* coord      = (const float*)d_in[1];
    const int*   eidx       = (const int*)d_in[2];   // [2][N_EDGES] int32
    const float* coord_diff = (const float*)d_in[3];
    const float* edge_attr  = (const float*)d_in[4];
    const float* node_mask  = (const float*)d_in[5];
    const float* edge_mask  = (const float*)d_in[6];
    const float* W1 = (const float*)d_in[7];
    const float* b1 = (const float*)d_in[8];
    const float* W2 = (const float*)d_in[9];
    const float* b2 = (const float*)d_in[10];
    const float* W3 = (const float*)d_in[11];
    float* out = (float*)d_out;

    uint16_t* At = (uint16_t*)d_ws;                        // 12.8 MB
    uint16_t* Bt = At + (size_t)N_NODES * 128;             // 12.8 MB
    float*   agg = (float*)(Bt + (size_t)N_NODES * 128);   // 600 KB

    hipMemsetAsync(agg, 0, N_NODES * 3 * sizeof(float), stream);

    precompute_AB<<<(N_NODES + 63) / 64, 256, 0, stream>>>(h, W1, b1, At, Bt);

    edge_kernel<<<1536, 256, 0, stream>>>(eidx, eidx + N_EDGES, edge_attr, edge_mask,
                                          coord_diff, W1, W2, b2, W3, At, Bt, agg);

    finalize_kernel<<<(N_NODES * 3 + 255) / 256, 256, 0, stream>>>(coord, agg, node_mask, out);
}

// Round 3
// 4876.378 us; speedup vs baseline: 1.0013x; 1.0013x over previous
//
#include <hip/hip_runtime.h>
#include <hip/hip_bf16.h>
#include <stdint.h>

#define N_NODES 50000
#define N_EDGES 1000000
#define HIDDEN 128

using short8  = __attribute__((ext_vector_type(8))) short;
using floatx4 = __attribute__((ext_vector_type(4))) float;

__device__ __forceinline__ float bf2f(uint16_t u) {
    return __uint_as_float(((uint32_t)u) << 16);
}
__device__ __forceinline__ uint16_t f2bf(float f) {
    uint32_t x = __float_as_uint(f);
    return (uint16_t)((x + 0x7FFFu + ((x >> 16) & 1u)) >> 16);
}
__device__ __forceinline__ uint32_t cvt_pk_bf16(float lo, float hi) {
    uint32_t r;
    asm("v_cvt_pk_bf16_f32 %0, %1, %2" : "=v"(r) : "v"(lo), "v"(hi));
    return r;
}
__device__ __forceinline__ float fast_silu(float x) {
    float e = __expf(-x);
    return x * __builtin_amdgcn_rcpf(1.0f + e);
}

// ---------------------------------------------------------------------------
// Kernel 1: At[n][k] = sum_j h[n][j]*W1[j][k] + b1[k]   (k<128)
//           Bt[n][k] = sum_j h[n][j]*W1[128+j][k]
// ---------------------------------------------------------------------------
__global__ __launch_bounds__(256) void precompute_AB(
    const float* __restrict__ h, const float* __restrict__ W1,
    const float* __restrict__ b1,
    uint16_t* __restrict__ At, uint16_t* __restrict__ Bt)
{
    __shared__ uint16_t w1t[256 * 128];  // [c][j] bf16, XOR-swizzled, 64 KB
    int t = threadIdx.x;
    for (int idx = t; idx < 256 * 128; idx += 256) {
        int c = idx >> 7, j = idx & 127;
        float v = (c < 128) ? W1[j * 128 + c] : W1[(128 + j) * 128 + (c - 128)];
        int byte_off = (c << 8) + (j << 1);
        byte_off ^= ((c & 7) << 4);
        *(uint16_t*)((char*)w1t + byte_off) = f2bf(v);
    }
    __syncthreads();

    int wave = t >> 6, lane = t & 63;
    int lrow = lane & 15, kg = lane >> 4;

    int nodeBase = blockIdx.x * 64 + wave * 16;
    int node = nodeBase + lrow;
    int nclamp = node < N_NODES ? node : N_NODES - 1;
    const float* hrow = h + (size_t)nclamp * 128;

    short8 afrag[4];
#pragma unroll
    for (int kk = 0; kk < 4; ++kk) {
        int k0 = kk * 32 + kg * 8;
        float4 f0 = *(const float4*)(hrow + k0);
        float4 f1 = *(const float4*)(hrow + k0 + 4);
        short8 a;
        uint32_t* ap = (uint32_t*)&a;
        ap[0] = cvt_pk_bf16(f0.x, f0.y);
        ap[1] = cvt_pk_bf16(f0.z, f0.w);
        ap[2] = cvt_pk_bf16(f1.x, f1.y);
        ap[3] = cvt_pk_bf16(f1.z, f1.w);
        afrag[kk] = a;
    }

    for (int nt = 0; nt < 16; ++nt) {
        floatx4 acc = {0.f, 0.f, 0.f, 0.f};
        int c = nt * 16 + lrow;
#pragma unroll
        for (int kk = 0; kk < 4; ++kk) {
            int byte_off = (c << 8) + ((kk * 32 + kg * 8) << 1);
            byte_off ^= ((c & 7) << 4);
            short8 b = *(const short8*)((const char*)w1t + byte_off);
            acc = __builtin_amdgcn_mfma_f32_16x16x32_bf16(afrag[kk], b, acc, 0, 0, 0);
        }
#pragma unroll
        for (int r = 0; r < 4; ++r) {
            int onode = nodeBase + kg * 4 + r;
            if (onode < N_NODES) {
                float v = acc[r];
                if (c < 128) {
                    At[(size_t)onode * 128 + c] = f2bf(v + b1[c]);
                } else {
                    Bt[(size_t)onode * 128 + (c - 128)] = f2bf(v);
                }
            }
        }
    }
}

// ---------------------------------------------------------------------------
// Kernel 2: per-edge fused MLP. One wave = 16 edges; software-pipelined
// gathers (next tile's At/Bt rows issued before current tile's layer-2).
// NOTE: no min-occupancy bound — the pipeline needs ~170 VGPRs; capping
// register count forces spills (round-2 disaster: VGPR=64, 17x slowdown).
// ---------------------------------------------------------------------------
__global__ __launch_bounds__(256) void edge_kernel(
    const int* __restrict__ rowIdx, const int* __restrict__ colIdx,
    const float* __restrict__ edge_attr, const float* __restrict__ edge_mask,
    const float* __restrict__ coord_diff,
    const float* __restrict__ W1, const float* __restrict__ W2,
    const float* __restrict__ b2, const float* __restrict__ W3,
    const uint16_t* __restrict__ At, const uint16_t* __restrict__ Bt,
    float* __restrict__ agg)
{
    __shared__ uint16_t w2t[128 * 128];  // [n][k] bf16, XOR-swizzled, 32 KB
    __shared__ float s_w1e[128], s_b2[128], s_w3[128];
    int t = threadIdx.x;
    for (int idx = t; idx < 128 * 128; idx += 256) {
        int n = idx >> 7, k = idx & 127;
        float v = W2[k * 128 + n];
        int byte_off = (n << 8) + (k << 1);
        byte_off ^= ((n & 7) << 4);
        *(uint16_t*)((char*)w2t + byte_off) = f2bf(v);
    }
    if (t < 128) { s_w1e[t] = W1[256 * 128 + t]; s_b2[t] = b2[t]; s_w3[t] = W3[t]; }
    __syncthreads();

    int wave = t >> 6, lane = t & 63;
    int lrow = lane & 15, kg = lane >> 4;

    const int numTiles = N_EDGES / 16;           // 62500
    int wavesTotal = gridDim.x * 4;
    int waveId = blockIdx.x * 4 + wave;
    if (waveId >= numTiles) return;

    // ---- prologue: load tile-0 indices + gathers ----
    int tile = waveId;
    int e0 = tile * 16 + lrow;
    int r = rowIdx[e0], c = colIdx[e0];
    float attr = edge_attr[e0];
    short8 ga[4], gb[4];
    {
        const uint16_t* arow = At + (size_t)r * 128;
        const uint16_t* brow = Bt + (size_t)c * 128;
#pragma unroll
        for (int kk = 0; kk < 4; ++kk) {
            int k0 = kk * 32 + kg * 8;
            ga[kk] = *(const short8*)(arow + k0);
            gb[kk] = *(const short8*)(brow + k0);
        }
    }

    while (true) {
        int ebase = tile * 16;
        int ntile = tile + wavesTotal;
        bool more = ntile < numTiles;
        int tclamp = more ? ntile : tile;
        // next tile's indices (latency hidden under layer-1)
        int ne = tclamp * 16 + lrow;
        int nr = rowIdx[ne], nc = colIdx[ne];
        float nattr = edge_attr[ne];

        // ---- layer 1: consume ga/gb -> afrag (silu'd bf16) ----
        short8 afrag[4];
#pragma unroll
        for (int kk = 0; kk < 4; ++kk) {
            int k0 = kk * 32 + kg * 8;
            float xs[8];
#pragma unroll
            for (int j = 0; j < 8; ++j) {
                float x = bf2f((uint16_t)ga[kk][j]) + bf2f((uint16_t)gb[kk][j])
                        + attr * s_w1e[k0 + j];
                xs[j] = fast_silu(x);
            }
            short8 u;
            uint32_t* up = (uint32_t*)&u;
            up[0] = cvt_pk_bf16(xs[0], xs[1]);
            up[1] = cvt_pk_bf16(xs[2], xs[3]);
            up[2] = cvt_pk_bf16(xs[4], xs[5]);
            up[3] = cvt_pk_bf16(xs[6], xs[7]);
            afrag[kk] = u;
        }

        // ---- issue next tile's gathers (hidden under layer-2) ----
        {
            const uint16_t* narow = At + (size_t)nr * 128;
            const uint16_t* nbrow = Bt + (size_t)nc * 128;
#pragma unroll
            for (int kk = 0; kk < 4; ++kk) {
                int k0 = kk * 32 + kg * 8;
                ga[kk] = *(const short8*)(narow + k0);
                gb[kk] = *(const short8*)(nbrow + k0);
            }
        }

        // ---- layer 2 + fused silu + W3 dot ----
        float pm0 = 0.f, pm1 = 0.f, pm2 = 0.f, pm3 = 0.f;
#pragma unroll
        for (int nt = 0; nt < 8; ++nt) {
            floatx4 acc = {0.f, 0.f, 0.f, 0.f};
            int n = nt * 16 + lrow;
#pragma unroll
            for (int kk = 0; kk < 4; ++kk) {
                int byte_off = (n << 8) + ((kk * 32 + kg * 8) << 1);
                byte_off ^= ((n & 7) << 4);
                short8 b = *(const short8*)((const char*)w2t + byte_off);
                acc = __builtin_amdgcn_mfma_f32_16x16x32_bf16(afrag[kk], b, acc, 0, 0, 0);
            }
            float w3v = s_w3[n], b2v = s_b2[n];
            pm0 += fast_silu(acc[0] + b2v) * w3v;
            pm1 += fast_silu(acc[1] + b2v) * w3v;
            pm2 += fast_silu(acc[2] + b2v) * w3v;
            pm3 += fast_silu(acc[3] + b2v) * w3v;
        }

        // reduce across the 16 lanes of each group
#pragma unroll
        for (int m = 1; m < 16; m <<= 1) {
            pm0 += __shfl_xor(pm0, m, 64);
            pm1 += __shfl_xor(pm1, m, 64);
            pm2 += __shfl_xor(pm2, m, 64);
            pm3 += __shfl_xor(pm3, m, 64);
        }
        // group kg holds m for edges ebase + kg*4 + {0..3} in pm0..pm3

        if (lrow < 12) {
            int rsel = lrow / 3;
            int dim = lrow - rsel * 3;
            float mval = (rsel == 0) ? pm0 : (rsel == 1) ? pm1 : (rsel == 2) ? pm2 : pm3;
            int eg = ebase + kg * 4 + rsel;
            float val = coord_diff[eg * 3 + dim] * mval * edge_mask[eg];
            int rnode = __shfl(r, kg * 4 + rsel, 16);
            atomicAdd(&agg[rnode * 3 + dim], val);
        }

        if (!more) break;
        tile = ntile;
        r = nr; c = nc; attr = nattr;
    }
}

// ---------------------------------------------------------------------------
// Kernel 3: out = (coord + agg/100) * node_mask
// ---------------------------------------------------------------------------
__global__ __launch_bounds__(256) void finalize_kernel(
    const float* __restrict__ coord, const float* __restrict__ agg,
    const float* __restrict__ node_mask, float* __restrict__ out)
{
    int i = blockIdx.x * 256 + threadIdx.x;
    if (i < N_NODES * 3) {
        out[i] = (coord[i] + agg[i] * 0.01f) * node_mask[i / 3];
    }
}

extern "C" void kernel_launch(void* const* d_in, const int* in_sizes, int n_in,
                              void* d_out, int out_size, void* d_ws, size_t ws_size,
                              hipStream_t stream) {
    const float* h          = (const float*)d_in[0];
    const float* coord      = (const float*)d_in[1];
    const int*   eidx       = (const int*)d_in[2];   // [2][N_EDGES] int32
    const float* coord_diff = (const float*)d_in[3];
    const float* edge_attr  = (const float*)d_in[4];
    const float* node_mask  = (const float*)d_in[5];
    const float* edge_mask  = (const float*)d_in[6];
    const float* W1 = (const float*)d_in[7];
    const float* b1 = (const float*)d_in[8];
    const float* W2 = (const float*)d_in[9];
    const float* b2 = (const float*)d_in[10];
    const float* W3 = (const float*)d_in[11];
    float* out = (float*)d_out;

    uint16_t* At = (uint16_t*)d_ws;                        // 12.8 MB
    uint16_t* Bt = At + (size_t)N_NODES * 128;             // 12.8 MB
    float*   agg = (float*)(Bt + (size_t)N_NODES * 128);   // 600 KB

    hipMemsetAsync(agg, 0, N_NODES * 3 * sizeof(float), stream);

    precompute_AB<<<(N_NODES + 63) / 64, 256, 0, stream>>>(h, W1, b1, At, Bt);

    edge_kernel<<<1536, 256, 0, stream>>>(eidx, eidx + N_EDGES, edge_attr, edge_mask,
                                          coord_diff, W1, W2, b2, W3, At, Bt, agg);

    finalize_kernel<<<(N_NODES * 3 + 255) / 256, 256, 0, stream>>>(coord, agg, node_mask, out);
}

// Round 4
// 234.243 us; speedup vs baseline: 20.8447x; 20.8176x over previous
//
#include <hip/hip_runtime.h>
#include <hip/hip_bf16.h>
#include <stdint.h>

#define N_NODES 50000
#define N_EDGES 1000000
#define HIDDEN 128

using short8  = __attribute__((ext_vector_type(8))) short;
using floatx4 = __attribute__((ext_vector_type(4))) float;

__device__ __forceinline__ float bf2f(uint16_t u) {
    return __uint_as_float(((uint32_t)u) << 16);
}
__device__ __forceinline__ uint16_t f2bf(float f) {
    uint32_t x = __float_as_uint(f);
    return (uint16_t)((x + 0x7FFFu + ((x >> 16) & 1u)) >> 16);
}
__device__ __forceinline__ uint32_t cvt_pk_bf16(float lo, float hi) {
    uint32_t r;
    asm("v_cvt_pk_bf16_f32 %0, %1, %2" : "=v"(r) : "v"(lo), "v"(hi));
    return r;
}
__device__ __forceinline__ float fast_silu(float x) {
    float e = __expf(-x);
    return x * __builtin_amdgcn_rcpf(1.0f + e);
}

// ---------------------------------------------------------------------------
// Kernel 1: At[n][k] = sum_j h[n][j]*W1[j][k] + b1[k]   (k<128)
//           Bt[n][k] = sum_j h[n][j]*W1[128+j][k]
// ---------------------------------------------------------------------------
__global__ __launch_bounds__(256) void precompute_AB(
    const float* __restrict__ h, const float* __restrict__ W1,
    const float* __restrict__ b1,
    uint16_t* __restrict__ At, uint16_t* __restrict__ Bt)
{
    __shared__ uint16_t w1t[256 * 128];  // [c][j] bf16, XOR-swizzled, 64 KB
    int t = threadIdx.x;
    for (int idx = t; idx < 256 * 128; idx += 256) {
        int c = idx >> 7, j = idx & 127;
        float v = (c < 128) ? W1[j * 128 + c] : W1[(128 + j) * 128 + (c - 128)];
        int byte_off = (c << 8) + (j << 1);
        byte_off ^= ((c & 7) << 4);
        *(uint16_t*)((char*)w1t + byte_off) = f2bf(v);
    }
    __syncthreads();

    int wave = t >> 6, lane = t & 63;
    int lrow = lane & 15, kg = lane >> 4;

    int nodeBase = blockIdx.x * 64 + wave * 16;
    int node = nodeBase + lrow;
    int nclamp = node < N_NODES ? node : N_NODES - 1;
    const float* hrow = h + (size_t)nclamp * 128;

    short8 afrag[4];
#pragma unroll
    for (int kk = 0; kk < 4; ++kk) {
        int k0 = kk * 32 + kg * 8;
        float4 f0 = *(const float4*)(hrow + k0);
        float4 f1 = *(const float4*)(hrow + k0 + 4);
        short8 a;
        uint32_t* ap = (uint32_t*)&a;
        ap[0] = cvt_pk_bf16(f0.x, f0.y);
        ap[1] = cvt_pk_bf16(f0.z, f0.w);
        ap[2] = cvt_pk_bf16(f1.x, f1.y);
        ap[3] = cvt_pk_bf16(f1.z, f1.w);
        afrag[kk] = a;
    }

    for (int nt = 0; nt < 16; ++nt) {
        floatx4 acc = {0.f, 0.f, 0.f, 0.f};
        int c = nt * 16 + lrow;
#pragma unroll
        for (int kk = 0; kk < 4; ++kk) {
            int byte_off = (c << 8) + ((kk * 32 + kg * 8) << 1);
            byte_off ^= ((c & 7) << 4);
            short8 b = *(const short8*)((const char*)w1t + byte_off);
            acc = __builtin_amdgcn_mfma_f32_16x16x32_bf16(afrag[kk], b, acc, 0, 0, 0);
        }
#pragma unroll
        for (int r = 0; r < 4; ++r) {
            int onode = nodeBase + kg * 4 + r;
            if (onode < N_NODES) {
                float v = acc[r];
                if (c < 128) {
                    At[(size_t)onode * 128 + c] = f2bf(v + b1[c]);
                } else {
                    Bt[(size_t)onode * 128 + (c - 128)] = f2bf(v);
                }
            }
        }
    }
}

// ---------------------------------------------------------------------------
// Kernel 2: per-edge fused MLP. One wave = 32 edges (two 16-edge MFMA tiles)
// per loop iteration. All 16 gather loads are issued at the top of the body;
// tile-1's loads hide under tile-0's compute. NO values live across the loop
// backedge (the round-2/3 rotating-pipeline variant collapsed regalloc to
// 64-72 VGPR + scratch spills, 17x slowdown).
// ---------------------------------------------------------------------------
__global__ __launch_bounds__(256) void edge_kernel(
    const int* __restrict__ rowIdx, const int* __restrict__ colIdx,
    const float* __restrict__ edge_attr, const float* __restrict__ edge_mask,
    const float* __restrict__ coord_diff,
    const float* __restrict__ W1, const float* __restrict__ W2,
    const float* __restrict__ b2, const float* __restrict__ W3,
    const uint16_t* __restrict__ At, const uint16_t* __restrict__ Bt,
    float* __restrict__ agg)
{
    __shared__ uint16_t w2t[128 * 128];  // [n][k] bf16, XOR-swizzled, 32 KB
    __shared__ float s_w1e[128], s_b2[128], s_w3[128];
    int t = threadIdx.x;
    for (int idx = t; idx < 128 * 128; idx += 256) {
        int n = idx >> 7, k = idx & 127;
        float v = W2[k * 128 + n];
        int byte_off = (n << 8) + (k << 1);
        byte_off ^= ((n & 7) << 4);
        *(uint16_t*)((char*)w2t + byte_off) = f2bf(v);
    }
    if (t < 128) { s_w1e[t] = W1[256 * 128 + t]; s_b2[t] = b2[t]; s_w3[t] = W3[t]; }
    __syncthreads();

    int wave = t >> 6, lane = t & 63;
    int lrow = lane & 15, kg = lane >> 4;

    const int numPairs = N_EDGES / 32;           // 31250
    int wavesTotal = gridDim.x * 4;
    int waveId = blockIdx.x * 4 + wave;

    for (int pair = waveId; pair < numPairs; pair += wavesTotal) {
        int ebase0 = pair * 32;
        int ebase1 = ebase0 + 16;
        int e0 = ebase0 + lrow;
        int e1 = ebase1 + lrow;
        int r0 = rowIdx[e0], c0 = colIdx[e0];
        int r1 = rowIdx[e1], c1 = colIdx[e1];
        float attr0 = edge_attr[e0];
        float attr1 = edge_attr[e1];

        // ---- issue ALL gathers up front (16 x 16B loads in flight) ----
        const uint16_t* ar0 = At + (size_t)r0 * 128;
        const uint16_t* br0 = Bt + (size_t)c0 * 128;
        const uint16_t* ar1 = At + (size_t)r1 * 128;
        const uint16_t* br1 = Bt + (size_t)c1 * 128;
        short8 ga0[4], gb0[4], ga1[4], gb1[4];
#pragma unroll
        for (int kk = 0; kk < 4; ++kk) {
            int k0 = kk * 32 + kg * 8;
            ga0[kk] = *(const short8*)(ar0 + k0);
            gb0[kk] = *(const short8*)(br0 + k0);
            ga1[kk] = *(const short8*)(ar1 + k0);
            gb1[kk] = *(const short8*)(br1 + k0);
        }

#pragma unroll
        for (int half = 0; half < 2; ++half) {
            int ebase = half ? ebase1 : ebase0;
            float attr = half ? attr1 : attr0;

            // ---- layer 1: gathered rows -> silu'd bf16 A-fragments ----
            short8 afrag[4];
#pragma unroll
            for (int kk = 0; kk < 4; ++kk) {
                int k0 = kk * 32 + kg * 8;
                short8 av = half ? ga1[kk] : ga0[kk];
                short8 bv = half ? gb1[kk] : gb0[kk];
                float xs[8];
#pragma unroll
                for (int j = 0; j < 8; ++j) {
                    float x = bf2f((uint16_t)av[j]) + bf2f((uint16_t)bv[j])
                            + attr * s_w1e[k0 + j];
                    xs[j] = fast_silu(x);
                }
                short8 u;
                uint32_t* up = (uint32_t*)&u;
                up[0] = cvt_pk_bf16(xs[0], xs[1]);
                up[1] = cvt_pk_bf16(xs[2], xs[3]);
                up[2] = cvt_pk_bf16(xs[4], xs[5]);
                up[3] = cvt_pk_bf16(xs[6], xs[7]);
                afrag[kk] = u;
            }

            // ---- layer 2 + fused silu + W3 dot ----
            float pm0 = 0.f, pm1 = 0.f, pm2 = 0.f, pm3 = 0.f;
#pragma unroll
            for (int nt = 0; nt < 8; ++nt) {
                floatx4 acc = {0.f, 0.f, 0.f, 0.f};
                int n = nt * 16 + lrow;
#pragma unroll
                for (int kk = 0; kk < 4; ++kk) {
                    int byte_off = (n << 8) + ((kk * 32 + kg * 8) << 1);
                    byte_off ^= ((n & 7) << 4);
                    short8 b = *(const short8*)((const char*)w2t + byte_off);
                    acc = __builtin_amdgcn_mfma_f32_16x16x32_bf16(afrag[kk], b, acc, 0, 0, 0);
                }
                float w3v = s_w3[n], b2v = s_b2[n];
                pm0 += fast_silu(acc[0] + b2v) * w3v;
                pm1 += fast_silu(acc[1] + b2v) * w3v;
                pm2 += fast_silu(acc[2] + b2v) * w3v;
                pm3 += fast_silu(acc[3] + b2v) * w3v;
            }

            // reduce across the 16 lanes of each group
#pragma unroll
            for (int m = 1; m < 16; m <<= 1) {
                pm0 += __shfl_xor(pm0, m, 64);
                pm1 += __shfl_xor(pm1, m, 64);
                pm2 += __shfl_xor(pm2, m, 64);
                pm3 += __shfl_xor(pm3, m, 64);
            }
            // group kg holds m for edges ebase + kg*4 + {0..3} in pm0..pm3

            if (lrow < 12) {
                int rsel = lrow / 3;
                int dim = lrow - rsel * 3;
                float mval = (rsel == 0) ? pm0 : (rsel == 1) ? pm1
                           : (rsel == 2) ? pm2 : pm3;
                int eg = ebase + kg * 4 + rsel;
                float val = coord_diff[eg * 3 + dim] * mval * edge_mask[eg];
                int rnode = rowIdx[eg];
                atomicAdd(&agg[rnode * 3 + dim], val);
            }
        }
    }
}

// ---------------------------------------------------------------------------
// Kernel 3: out = (coord + agg/100) * node_mask
// ---------------------------------------------------------------------------
__global__ __launch_bounds__(256) void finalize_kernel(
    const float* __restrict__ coord, const float* __restrict__ agg,
    const float* __restrict__ node_mask, float* __restrict__ out)
{
    int i = blockIdx.x * 256 + threadIdx.x;
    if (i < N_NODES * 3) {
        out[i] = (coord[i] + agg[i] * 0.01f) * node_mask[i / 3];
    }
}

extern "C" void kernel_launch(void* const* d_in, const int* in_sizes, int n_in,
                              void* d_out, int out_size, void* d_ws, size_t ws_size,
                              hipStream_t stream) {
    const float* h          = (const float*)d_in[0];
    const float* coord      = (const float*)d_in[1];
    const int*   eidx       = (const int*)d_in[2];   // [2][N_EDGES] int32
    const float* coord_diff = (const float*)d_in[3];
    const float* edge_attr  = (const float*)d_in[4];
    const float* node_mask  = (const float*)d_in[5];
    const float* edge_mask  = (const float*)d_in[6];
    const float* W1 = (const float*)d_in[7];
    const float* b1 = (const float*)d_in[8];
    const float* W2 = (const float*)d_in[9];
    const float* b2 = (const float*)d_in[10];
    const float* W3 = (const float*)d_in[11];
    float* out = (float*)d_out;

    uint16_t* At = (uint16_t*)d_ws;                        // 12.8 MB
    uint16_t* Bt = At + (size_t)N_NODES * 128;             // 12.8 MB
    float*   agg = (float*)(Bt + (size_t)N_NODES * 128);   // 600 KB

    hipMemsetAsync(agg, 0, N_NODES * 3 * sizeof(float), stream);

    precompute_AB<<<(N_NODES + 63) / 64, 256, 0, stream>>>(h, W1, b1, At, Bt);

    edge_kernel<<<2048, 256, 0, stream>>>(eidx, eidx + N_EDGES, edge_attr, edge_mask,
                                          coord_diff, W1, W2, b2, W3, At, Bt, agg);

    finalize_kernel<<<(N_NODES * 3 + 255) / 256, 256, 0, stream>>>(coord, agg, node_mask, out);
}

// Round 5
// 183.811 us; speedup vs baseline: 26.5638x; 1.2744x over previous
//
#include <hip/hip_runtime.h>
#include <hip/hip_bf16.h>
#include <stdint.h>

#define N_NODES 50000
#define N_EDGES 1000000
#define HIDDEN 128

using short8  = __attribute__((ext_vector_type(8))) short;
using floatx4 = __attribute__((ext_vector_type(4))) float;

__device__ __forceinline__ float bf2f(uint16_t u) {
    return __uint_as_float(((uint32_t)u) << 16);
}
__device__ __forceinline__ uint16_t f2bf(float f) {
    uint32_t x = __float_as_uint(f);
    return (uint16_t)((x + 0x7FFFu + ((x >> 16) & 1u)) >> 16);
}
__device__ __forceinline__ uint32_t cvt_pk_bf16(float lo, float hi) {
    uint32_t r;
    asm("v_cvt_pk_bf16_f32 %0, %1, %2" : "=v"(r) : "v"(lo), "v"(hi));
    return r;
}
__device__ __forceinline__ float fast_silu(float x) {
    float e = __expf(-x);
    return x * __builtin_amdgcn_rcpf(1.0f + e);
}

// ---------------------------------------------------------------------------
// Kernel 1: At[n][k] = sum_j h[n][j]*W1[j][k] + b1[k]   (k<128)
//           Bt[n][k] = sum_j h[n][j]*W1[128+j][k]
// 128 nodes per block (2 groups of 64) to amortize the 64KB W1 staging.
// ---------------------------------------------------------------------------
__global__ __launch_bounds__(256) void precompute_AB(
    const float* __restrict__ h, const float* __restrict__ W1,
    const float* __restrict__ b1,
    uint16_t* __restrict__ At, uint16_t* __restrict__ Bt)
{
    __shared__ uint16_t w1t[256 * 128];  // [c][j] bf16, XOR-swizzled, 64 KB
    int t = threadIdx.x;
    for (int idx = t; idx < 256 * 128; idx += 256) {
        int c = idx >> 7, j = idx & 127;
        float v = (c < 128) ? W1[j * 128 + c] : W1[(128 + j) * 128 + (c - 128)];
        int byte_off = (c << 8) + (j << 1);
        byte_off ^= ((c & 7) << 4);
        *(uint16_t*)((char*)w1t + byte_off) = f2bf(v);
    }
    __syncthreads();

    int wave = t >> 6, lane = t & 63;
    int lrow = lane & 15, kg = lane >> 4;

    for (int g = 0; g < 2; ++g) {
        int nodeBase = blockIdx.x * 128 + g * 64 + wave * 16;
        if (nodeBase >= N_NODES) break;
        int node = nodeBase + lrow;
        int nclamp = node < N_NODES ? node : N_NODES - 1;
        const float* hrow = h + (size_t)nclamp * 128;

        short8 afrag[4];
#pragma unroll
        for (int kk = 0; kk < 4; ++kk) {
            int k0 = kk * 32 + kg * 8;
            float4 f0 = *(const float4*)(hrow + k0);
            float4 f1 = *(const float4*)(hrow + k0 + 4);
            short8 a;
            uint32_t* ap = (uint32_t*)&a;
            ap[0] = cvt_pk_bf16(f0.x, f0.y);
            ap[1] = cvt_pk_bf16(f0.z, f0.w);
            ap[2] = cvt_pk_bf16(f1.x, f1.y);
            ap[3] = cvt_pk_bf16(f1.z, f1.w);
            afrag[kk] = a;
        }

        for (int nt = 0; nt < 16; ++nt) {
            floatx4 acc = {0.f, 0.f, 0.f, 0.f};
            int c = nt * 16 + lrow;
#pragma unroll
            for (int kk = 0; kk < 4; ++kk) {
                int byte_off = (c << 8) + ((kk * 32 + kg * 8) << 1);
                byte_off ^= ((c & 7) << 4);
                short8 b = *(const short8*)((const char*)w1t + byte_off);
                acc = __builtin_amdgcn_mfma_f32_16x16x32_bf16(afrag[kk], b, acc, 0, 0, 0);
            }
#pragma unroll
            for (int r = 0; r < 4; ++r) {
                int onode = nodeBase + kg * 4 + r;
                if (onode < N_NODES) {
                    float v = acc[r];
                    if (c < 128) {
                        At[(size_t)onode * 128 + c] = f2bf(v + b1[c]);
                    } else {
                        Bt[(size_t)onode * 128 + (c - 128)] = f2bf(v);
                    }
                }
            }
        }
    }
}

// ---------------------------------------------------------------------------
// Kernel 2: per-edge fused MLP. 512-thr blocks (8 waves share one 32KB w2t ->
// 24-32 waves/CU vs 16 at 256-thr). One wave = 32 edges (two 16-edge tiles);
// half-0's 8 gathers issued FIRST, then half-1's 8 (so half-0 compute waits
// only vmcnt(8) and half-1's loads fly underneath). No values live across
// the loop backedge (regalloc hazard, rounds 2-3).
// ---------------------------------------------------------------------------
__global__ __launch_bounds__(512) void edge_kernel(
    const int* __restrict__ rowIdx, const int* __restrict__ colIdx,
    const float* __restrict__ edge_attr, const float* __restrict__ edge_mask,
    const float* __restrict__ coord_diff,
    const float* __restrict__ W1, const float* __restrict__ W2,
    const float* __restrict__ b2, const float* __restrict__ W3,
    const uint16_t* __restrict__ At, const uint16_t* __restrict__ Bt,
    float* __restrict__ agg)
{
    __shared__ uint16_t w2t[128 * 128];  // [n][k] bf16, XOR-swizzled, 32 KB
    __shared__ float s_w1e[128], s_b2[128], s_w3[128];
    int t = threadIdx.x;
    for (int idx = t; idx < 128 * 128; idx += 512) {
        int n = idx >> 7, k = idx & 127;
        float v = W2[k * 128 + n];
        int byte_off = (n << 8) + (k << 1);
        byte_off ^= ((n & 7) << 4);
        *(uint16_t*)((char*)w2t + byte_off) = f2bf(v);
    }
    if (t < 128) { s_w1e[t] = W1[256 * 128 + t]; s_b2[t] = b2[t]; s_w3[t] = W3[t]; }
    __syncthreads();

    int wave = t >> 6, lane = t & 63;
    int lrow = lane & 15, kg = lane >> 4;

    const int numPairs = N_EDGES / 32;           // 31250
    int wavesTotal = gridDim.x * 8;
    int waveId = blockIdx.x * 8 + wave;

    for (int pair = waveId; pair < numPairs; pair += wavesTotal) {
        int ebase0 = pair * 32;
        int ebase1 = ebase0 + 16;
        int e0 = ebase0 + lrow;
        int e1 = ebase1 + lrow;
        int r0 = rowIdx[e0], c0 = colIdx[e0];
        int r1 = rowIdx[e1], c1 = colIdx[e1];
        float attr0 = edge_attr[e0];
        float attr1 = edge_attr[e1];

        // ---- half-0 gathers first, then half-1 (issue order matters) ----
        const uint16_t* ar0 = At + (size_t)r0 * 128;
        const uint16_t* br0 = Bt + (size_t)c0 * 128;
        short8 ga0[4], gb0[4];
#pragma unroll
        for (int kk = 0; kk < 4; ++kk) {
            int k0 = kk * 32 + kg * 8;
            ga0[kk] = *(const short8*)(ar0 + k0);
            gb0[kk] = *(const short8*)(br0 + k0);
        }
        const uint16_t* ar1 = At + (size_t)r1 * 128;
        const uint16_t* br1 = Bt + (size_t)c1 * 128;
        short8 ga1[4], gb1[4];
#pragma unroll
        for (int kk = 0; kk < 4; ++kk) {
            int k0 = kk * 32 + kg * 8;
            ga1[kk] = *(const short8*)(ar1 + k0);
            gb1[kk] = *(const short8*)(br1 + k0);
        }

#pragma unroll
        for (int half = 0; half < 2; ++half) {
            int ebase = half ? ebase1 : ebase0;
            float attr = half ? attr1 : attr0;

            // ---- layer 1: gathered rows -> silu'd bf16 A-fragments ----
            short8 afrag[4];
#pragma unroll
            for (int kk = 0; kk < 4; ++kk) {
                int k0 = kk * 32 + kg * 8;
                short8 av = half ? ga1[kk] : ga0[kk];
                short8 bv = half ? gb1[kk] : gb0[kk];
                float xs[8];
#pragma unroll
                for (int j = 0; j < 8; ++j) {
                    float x = bf2f((uint16_t)av[j]) + bf2f((uint16_t)bv[j])
                            + attr * s_w1e[k0 + j];
                    xs[j] = fast_silu(x);
                }
                short8 u;
                uint32_t* up = (uint32_t*)&u;
                up[0] = cvt_pk_bf16(xs[0], xs[1]);
                up[1] = cvt_pk_bf16(xs[2], xs[3]);
                up[2] = cvt_pk_bf16(xs[4], xs[5]);
                up[3] = cvt_pk_bf16(xs[6], xs[7]);
                afrag[kk] = u;
            }

            // ---- layer 2 + fused silu + W3 dot (b2 folded into C) ----
            float pm0 = 0.f, pm1 = 0.f, pm2 = 0.f, pm3 = 0.f;
#pragma unroll
            for (int nt = 0; nt < 8; ++nt) {
                int n = nt * 16 + lrow;
                float b2v = s_b2[n];
                floatx4 acc = {b2v, b2v, b2v, b2v};
#pragma unroll
                for (int kk = 0; kk < 4; ++kk) {
                    int byte_off = (n << 8) + ((kk * 32 + kg * 8) << 1);
                    byte_off ^= ((n & 7) << 4);
                    short8 b = *(const short8*)((const char*)w2t + byte_off);
                    acc = __builtin_amdgcn_mfma_f32_16x16x32_bf16(afrag[kk], b, acc, 0, 0, 0);
                }
                float w3v = s_w3[n];
                pm0 += fast_silu(acc[0]) * w3v;
                pm1 += fast_silu(acc[1]) * w3v;
                pm2 += fast_silu(acc[2]) * w3v;
                pm3 += fast_silu(acc[3]) * w3v;
            }

            // reduce across the 16 lanes of each group
#pragma unroll
            for (int m = 1; m < 16; m <<= 1) {
                pm0 += __shfl_xor(pm0, m, 64);
                pm1 += __shfl_xor(pm1, m, 64);
                pm2 += __shfl_xor(pm2, m, 64);
                pm3 += __shfl_xor(pm3, m, 64);
            }
            // group kg holds m for edges ebase + kg*4 + {0..3} in pm0..pm3

            if (lrow < 12) {
                int rsel = lrow / 3;
                int dim = lrow - rsel * 3;
                float mval = (rsel == 0) ? pm0 : (rsel == 1) ? pm1
                           : (rsel == 2) ? pm2 : pm3;
                int eg = ebase + kg * 4 + rsel;
                float val = coord_diff[eg * 3 + dim] * mval * edge_mask[eg];
                int rnode = rowIdx[eg];
                atomicAdd(&agg[rnode * 3 + dim], val);
            }
        }
    }
}

// ---------------------------------------------------------------------------
// Kernel 3: out = (coord + agg/100) * node_mask
// ---------------------------------------------------------------------------
__global__ __launch_bounds__(256) void finalize_kernel(
    const float* __restrict__ coord, const float* __restrict__ agg,
    const float* __restrict__ node_mask, float* __restrict__ out)
{
    int i = blockIdx.x * 256 + threadIdx.x;
    if (i < N_NODES * 3) {
        out[i] = (coord[i] + agg[i] * 0.01f) * node_mask[i / 3];
    }
}

extern "C" void kernel_launch(void* const* d_in, const int* in_sizes, int n_in,
                              void* d_out, int out_size, void* d_ws, size_t ws_size,
                              hipStream_t stream) {
    const float* h          = (const float*)d_in[0];
    const float* coord      = (const float*)d_in[1];
    const int*   eidx       = (const int*)d_in[2];   // [2][N_EDGES] int32
    const float* coord_diff = (const float*)d_in[3];
    const float* edge_attr  = (const float*)d_in[4];
    const float* node_mask  = (const float*)d_in[5];
    const float* edge_mask  = (const float*)d_in[6];
    const float* W1 = (const float*)d_in[7];
    const float* b1 = (const float*)d_in[8];
    const float* W2 = (const float*)d_in[9];
    const float* b2 = (const float*)d_in[10];
    const float* W3 = (const float*)d_in[11];
    float* out = (float*)d_out;

    uint16_t* At = (uint16_t*)d_ws;                        // 12.8 MB
    uint16_t* Bt = At + (size_t)N_NODES * 128;             // 12.8 MB
    float*   agg = (float*)(Bt + (size_t)N_NODES * 128);   // 600 KB

    hipMemsetAsync(agg, 0, N_NODES * 3 * sizeof(float), stream);

    precompute_AB<<<(N_NODES + 127) / 128, 256, 0, stream>>>(h, W1, b1, At, Bt);

    edge_kernel<<<1024, 512, 0, stream>>>(eidx, eidx + N_EDGES, edge_attr, edge_mask,
                                          coord_diff, W1, W2, b2, W3, At, Bt, agg);

    finalize_kernel<<<(N_NODES * 3 + 255) / 256, 256, 0, stream>>>(coord, agg, node_mask, out);
}